// Round 4
// baseline (5061.517 us; speedup 1.0000x reference)
//
#include <hip/hip_runtime.h>
#include <hip/hip_bf16.h>
#include <hip/hip_fp16.h>

// Masked-reset LSTM — register-resident-weight GEMV formulation (R3 rewrite).
//
// Dims: OBS=64, EMBED=128, HIDDEN=256, B=32, T=2048, N=65536.
//
// R3 analysis: old 16-slot batched design was critical-path bound:
// longest segment (~88 steps) rode in a full 16-slot WG at ~33 us/step
// (VALUBusy 12.7%, Occ 2.7%). New design:
//  - fold embedding: z = [obs;h] @ Wg[320x1024] + bc   (Wg = [W_embed@kernel ; rec])
//  - ONE segment per WG, 1024 threads, thread j owns gate column j
//  - Wg column j lives in 160 u32 VGPRs as f16 pairs (loaded once per WG,
//    reused across every step -> weight traffic off the per-step path)
//  - per step: x=[obs_f16(64); h_f16(256)] broadcast from LDS, 160 dot2/thread,
//    z -> LDS, gates on threads<256, h -> LDS. ~0.5 us/step per CU.
//  - sorted-descending segment queue + atomic work stealing = LPT balance.

#define T_SEQ   2048
#define NBATCH  32
#define OBS     64
#define HID     256
#define KROWS   320
#define KP      160          // f16 pairs per column
#define MAXSEG  65536
#define NWG     512

// ---------------- math helpers (same as R1 passing version) ----------------
__device__ __forceinline__ float sigm(float x) {
    x = fminf(fmaxf(x, -30.f), 30.f);
    return 1.f / (1.f + __expf(-x));
}
__device__ __forceinline__ float tanh_(float x) {
    x = fminf(fmaxf(x, -15.f), 15.f);
    float e = __expf(2.f * x);
    return (e - 1.f) / (e + 1.f);
}

// packed f16x2 dot with fp32 accumulate
typedef _Float16 h2_t __attribute__((ext_vector_type(2)));
__device__ __forceinline__ float dot2(unsigned w, unsigned x, float acc) {
#if defined(__has_builtin) && __has_builtin(__builtin_amdgcn_fdot2)
    return __builtin_amdgcn_fdot2(__builtin_bit_cast(h2_t, w),
                                  __builtin_bit_cast(h2_t, x), acc, false);
#else
    float wl = __half2float(__ushort_as_half((unsigned short)(w & 0xffffu)));
    float wh = __half2float(__ushort_as_half((unsigned short)(w >> 16)));
    float xl = __half2float(__ushort_as_half((unsigned short)(x & 0xffffu)));
    float xh = __half2float(__ushort_as_half((unsigned short)(x >> 16)));
    return fmaf(wh, xh, fmaf(wl, xl, acc));
#endif
}

__device__ __forceinline__ unsigned packh(float a, float b) {
    return (unsigned)__half_as_ushort(__float2half(a)) |
           ((unsigned)__half_as_ushort(__float2half(b)) << 16);
}

// ---------------- prep: build packed Wp[kp][j], bc[j]; zero counters ----------
// grid 161 x 1024. kp<32: obs-part rows (W_embed@kernel), kp in [32,160): rec rows,
// kp==160: bc = bias + b_embed@kernel, and counter zeroing.
__global__ void prep_kernel(const float* __restrict__ W_embed, const float* __restrict__ b_embed,
                            const float* __restrict__ kern,    const float* __restrict__ rec,
                            const float* __restrict__ bias,
                            unsigned* __restrict__ Wp, float* __restrict__ bc,
                            unsigned* __restrict__ cnt) {
    int kp = blockIdx.x, j = threadIdx.x;
    if (kp < 32) {
        int r0 = 2 * kp, r1 = 2 * kp + 1;
        float wa = 0.f, wb = 0.f;
        #pragma unroll 8
        for (int k = 0; k < 128; ++k) {
            float kv = kern[k * 1024 + j];
            wa = fmaf(W_embed[r0 * 128 + k], kv, wa);
            wb = fmaf(W_embed[r1 * 128 + k], kv, wb);
        }
        Wp[kp * 1024 + j] = packh(wa, wb);
    } else if (kp < 160) {
        int k0 = 2 * (kp - 32);
        float wa = rec[(size_t)k0 * 1024 + j];
        float wb = rec[(size_t)(k0 + 1) * 1024 + j];
        Wp[kp * 1024 + j] = packh(wa, wb);
    } else {
        float acc = bias[j];
        for (int k = 0; k < 128; ++k)
            acc = fmaf(b_embed[k], kern[k * 1024 + j], acc);
        bc[j] = acc;
        if (j < 16) cnt[j] = 0u;
    }
}

// ---------------- segment extraction ----------------
__global__ void seg_kernel(const float* __restrict__ M, uint2* __restrict__ segs,
                           unsigned* __restrict__ cnt) {
    int b = blockIdx.x, tid = threadIdx.x;
    int base = b * T_SEQ;
    for (int t = tid; t < T_SEQ; t += 256) {
        bool start = (t == 0) || (M[base + t] != 0.f);
        if (!start) continue;
        int t2 = t + 1;
        while (t2 < T_SEQ && M[base + t2] == 0.f) ++t2;
        unsigned idx = atomicAdd(&cnt[0], 1u);
        segs[idx] = make_uint2((unsigned)(base + t), (unsigned)(t2 - t));
    }
}

// ---------------- counting sort by length, descending (LPT order) ----------------
__global__ void sort_kernel(const uint2* __restrict__ segs, uint2* __restrict__ out,
                            unsigned* __restrict__ cnt) {
    __shared__ unsigned hist[2049];
    __shared__ unsigned partial[256];
    __shared__ unsigned ofs[2049];
    int tid = threadIdx.x;
    unsigned n = cnt[0];
    for (int i = tid; i < 2049; i += 256) hist[i] = 0u;
    __syncthreads();
    for (unsigned i = tid; i < n; i += 256) atomicAdd(&hist[segs[i].y], 1u);
    __syncthreads();
    int cs = tid * 8 + 1;
    unsigned s = 0;
    #pragma unroll
    for (int i = 0; i < 8; ++i) s += hist[cs + i];
    partial[tid] = s;
    __syncthreads();
    if (tid == 0) {
        unsigned run = 0;
        for (int t = 255; t >= 0; --t) { unsigned p = partial[t]; partial[t] = run; run += p; }
    }
    __syncthreads();
    unsigned run = partial[tid];
    #pragma unroll
    for (int i = 7; i >= 0; --i) { int bin = cs + i; ofs[bin] = run; run += hist[bin]; }
    __syncthreads();
    for (unsigned i = tid; i < n; i += 256) {
        uint2 sg = segs[i];
        unsigned pos = atomicAdd(&ofs[sg.y], 1u);
        out[pos] = sg;
    }
}

// ---------------- persistent one-segment-per-WG LSTM ----------------
__global__ __launch_bounds__(1024, 8)
void lstm_kernel(const float* __restrict__ obs, const float* __restrict__ S,
                 const float* __restrict__ M,
                 const unsigned* __restrict__ Wp, const float* __restrict__ bc,
                 const uint2* __restrict__ segs, unsigned* __restrict__ cnt,
                 float* __restrict__ out) {
    __shared__ uint4 X4[KP / 4];          // f16 pairs: [0..31]=obs, [32..159]=h
    __shared__ float zb[1024];
    __shared__ unsigned sh_idx;
    __half* Xh = (__half*)X4;

    const int tid = threadIdx.x;
    const unsigned nseg = cnt[0];

    // column j's weights: 160 f16-pairs, register-resident for the whole kernel
    unsigned w[KP];
    {
        const unsigned* wp = Wp + tid;
        #pragma unroll
        for (int kp = 0; kp < KP; ++kp) w[kp] = wp[kp << 10];
    }
    const float bcj = bc[tid];

    float c = 0.f;
    for (;;) {
        if (tid == 0) sh_idx = atomicAdd(&cnt[1], 1u);
        __syncthreads();
        unsigned idx = sh_idx;
        if (idx >= nseg) break;
        uint2 sg = segs[idx];
        unsigned n0 = sg.x, n1 = sg.x + sg.y;

        // init state: chain start (t==0, no reset) -> S[b]; else zeros.
        // interior steps of a segment have M==0 by construction.
        if (tid < HID) {
            float h0 = 0.f;
            c = 0.f;
            if ((n0 & (T_SEQ - 1)) == 0u && M[n0] == 0.f) {
                unsigned b = n0 >> 11;
                h0 = S[b * 512 + tid];
                c  = S[b * 512 + 256 + tid];
            }
            Xh[OBS + tid] = __float2half(h0);
        }
        // barrier A inside the loop orders the init/h writes before the dots

        for (unsigned n = n0; n < n1; ++n) {
            if (tid < OBS) Xh[tid] = __float2half(obs[(size_t)n * OBS + tid]);
            __syncthreads();                           // A: X (obs+h) ready
            float a0 = bcj, a1 = 0.f, a2 = 0.f, a3 = 0.f;
            #pragma unroll
            for (int q = 0; q < KP / 4; ++q) {
                uint4 xv = X4[q];
                a0 = dot2(w[q * 4 + 0], xv.x, a0);
                a1 = dot2(w[q * 4 + 1], xv.y, a1);
                a2 = dot2(w[q * 4 + 2], xv.z, a2);
                a3 = dot2(w[q * 4 + 3], xv.w, a3);
            }
            zb[tid] = (a0 + a1) + (a2 + a3);
            __syncthreads();                           // B: z ready, X reads done
            if (tid < HID) {
                float zi = zb[tid], zf = zb[tid + 256];
                float zg = zb[tid + 512], zo = zb[tid + 768];
                float i = sigm(zi);
                float f = sigm(zf);
                float g = tanh_(zg);
                float o = sigm(zo);
                c = fmaf(f, c, i * g);
                float h = o * tanh_(c);
                Xh[OBS + tid] = __float2half(h);
                out[(size_t)n * HID + tid] = h;
            }
            // next iter's barrier A orders h/obs writes vs dot reads;
            // barrier A also orders gate-phase zb reads vs next zb writes.
        }
    }
}

// ---------------- launch ----------------
extern "C" void kernel_launch(void* const* d_in, const int* in_sizes, int n_in,
                              void* d_out, int out_size, void* d_ws, size_t ws_size,
                              hipStream_t stream) {
    const float* obs     = (const float*)d_in[0];
    const float* S       = (const float*)d_in[1];
    const float* M       = (const float*)d_in[2];
    const float* W_embed = (const float*)d_in[3];
    const float* b_embed = (const float*)d_in[4];
    const float* kern    = (const float*)d_in[5];
    const float* rec     = (const float*)d_in[6];
    const float* bias    = (const float*)d_in[7];
    float* out = (float*)d_out;

    // ws layout: Wp u32[160*1024] | bc f32[1024] | cnt u32[16] | segs | ssort
    unsigned* Wp    = (unsigned*)d_ws;
    float*    bc    = (float*)(Wp + KP * 1024);
    unsigned* cnt   = (unsigned*)(bc + 1024);
    uint2*    segs  = (uint2*)(cnt + 16);
    uint2*    ssort = segs + MAXSEG;
    // total ~1.7 MB

    hipLaunchKernelGGL(prep_kernel, dim3(161), dim3(1024), 0, stream,
                       W_embed, b_embed, kern, rec, bias, Wp, bc, cnt);
    hipLaunchKernelGGL(seg_kernel, dim3(NBATCH), dim3(256), 0, stream, M, segs, cnt);
    hipLaunchKernelGGL(sort_kernel, dim3(1), dim3(256), 0, stream, segs, ssort, cnt);
    hipLaunchKernelGGL(lstm_kernel, dim3(NWG), dim3(1024), 0, stream,
                       obs, S, M, Wp, bc, ssort, cnt, out);
}

// Round 6
// 2940.250 us; speedup vs baseline: 1.7215x; 1.7215x over previous
//
#include <hip/hip_runtime.h>
#include <hip/hip_bf16.h>
#include <hip/hip_fp16.h>

// Masked-reset LSTM — R5: batched-slot WG (R1 control flow) + f16 dot2 compute,
// obs-GEMM precompute, 2 WGs/CU.  (R4 resubmit + zx4 indexing bugfix.)
//
// Dims: OBS=64, EMBED=128, HIDDEN=256, B=32, T=2048, N=65536.
//
// R3 lesson (counters): 1024-thr WG with "register" weights spilled (VGPR=32,
// 15 GB scratch fetch). Weights CANNOT be register/LDS-resident (f16 = 640 KB
// > 512 KB VGPR file > 160 KB LDS). They must stream from L2 each step ->
// batch slots (16) to amortize, keep per-step VALU small, shrink bytes (f16,
// obs part precomputed).
//
// Layouts:
//   W4[k2][j]  (uint4, k2=0..159): 4 gates' f16 weight-pairs for column j.
//              k2<32: obs rows (W_embed@kernel pairs), k2>=32: rec rows.
//   bc4[j]     (float4): bias + b_embed@kernel, gate-grouped.
//   zx4[n][j]  (uint2): 4 gates' f16 obs-contribution (incl bias), if ws fits.
//   X[g][k2]   (LDS u32): f16 pairs; [0..31]=obs (no-zx path), [32..159]=h.
//   c[16]      per-thread registers (thread j owns h column j).

#define T_SEQ   2048
#define NBATCH  32
#define OBS     64
#define HID     256
#define GSLOTS  16
#define NK2     160
#define ZK2     32           // k2 where h-part starts
#define MAXSEG  65536
#define NWG     512

// ---------------- math helpers ----------------
__device__ __forceinline__ float sigm(float x) {
    x = fminf(fmaxf(x, -30.f), 30.f);
    return 1.f / (1.f + __expf(-x));
}
__device__ __forceinline__ float tanh_(float x) {
    x = fminf(fmaxf(x, -15.f), 15.f);
    float e = __expf(2.f * x);
    return (e - 1.f) / (e + 1.f);
}

typedef _Float16 h2_t __attribute__((ext_vector_type(2)));
__device__ __forceinline__ float dot2(unsigned w, unsigned x, float acc) {
#if defined(__has_builtin) && __has_builtin(__builtin_amdgcn_fdot2)
    return __builtin_amdgcn_fdot2(__builtin_bit_cast(h2_t, w),
                                  __builtin_bit_cast(h2_t, x), acc, false);
#else
    float wl = __half2float(__ushort_as_half((unsigned short)(w & 0xffffu)));
    float wh = __half2float(__ushort_as_half((unsigned short)(w >> 16)));
    float xl = __half2float(__ushort_as_half((unsigned short)(x & 0xffffu)));
    float xh = __half2float(__ushort_as_half((unsigned short)(x >> 16)));
    return fmaf(wh, xh, fmaf(wl, xl, acc));
#endif
}
__device__ __forceinline__ unsigned packh(float a, float b) {
    return (unsigned)__half_as_ushort(__float2half(a)) |
           ((unsigned)__half_as_ushort(__float2half(b)) << 16);
}

// ---------------- prep: W4, bc4, counters ----------------
// blocks 0..31: obs-part k2=b; 32..159: rec k2=b; 160: bc4 + cnt.
__global__ void prep_kernel(const float* __restrict__ W_embed, const float* __restrict__ b_embed,
                            const float* __restrict__ kern,    const float* __restrict__ rec,
                            const float* __restrict__ bias,
                            uint4* __restrict__ W4, float4* __restrict__ bc4,
                            unsigned* __restrict__ cnt) {
    int b = blockIdx.x, j = threadIdx.x;
    if (b < ZK2) {
        int r0 = 2 * b, r1 = r0 + 1;
        float d0[4] = {0.f, 0.f, 0.f, 0.f}, d1[4] = {0.f, 0.f, 0.f, 0.f};
        for (int k = 0; k < 128; ++k) {
            float e0 = W_embed[r0 * 128 + k], e1 = W_embed[r1 * 128 + k];
            #pragma unroll
            for (int q = 0; q < 4; ++q) {
                float kv = kern[k * 1024 + (q << 8) + j];
                d0[q] = fmaf(e0, kv, d0[q]);
                d1[q] = fmaf(e1, kv, d1[q]);
            }
        }
        W4[b * 256 + j] = make_uint4(packh(d0[0], d1[0]), packh(d0[1], d1[1]),
                                     packh(d0[2], d1[2]), packh(d0[3], d1[3]));
    } else if (b < NK2) {
        size_t k0 = (size_t)2 * (b - ZK2), k1 = k0 + 1;
        W4[b * 256 + j] = make_uint4(
            packh(rec[k0 * 1024 + j],       rec[k1 * 1024 + j]),
            packh(rec[k0 * 1024 + 256 + j], rec[k1 * 1024 + 256 + j]),
            packh(rec[k0 * 1024 + 512 + j], rec[k1 * 1024 + 512 + j]),
            packh(rec[k0 * 1024 + 768 + j], rec[k1 * 1024 + 768 + j]));
    } else {
        float a[4];
        #pragma unroll
        for (int q = 0; q < 4; ++q) a[q] = bias[(q << 8) + j];
        for (int k = 0; k < 128; ++k) {
            float e = b_embed[k];
            #pragma unroll
            for (int q = 0; q < 4; ++q)
                a[q] = fmaf(e, kern[k * 1024 + (q << 8) + j], a[q]);
        }
        bc4[j] = make_float4(a[0], a[1], a[2], a[3]);
        if (j < 16) cnt[j] = 0u;
    }
}

// ---------------- zx precompute: zx4[n][j] = obs[n]@Wc + bc (f16 gate pairs) ----
__global__ __launch_bounds__(256, 2)
void zx_kernel(const float* __restrict__ obs, const uint4* __restrict__ W4,
               const float4* __restrict__ bc4, uint2* __restrict__ zx4) {
    __shared__ __half obsh[64][64];                    // 8 KB
    const int tid = threadIdx.x;
    const size_t base = (size_t)blockIdx.x * 64 * 64;  // obs elem offset
    const size_t row0 = (size_t)blockIdx.x * 64;       // first timestep of block
    for (int i = tid; i < 4096; i += 256)
        obsh[i >> 6][i & 63] = __float2half(obs[base + i]);
    __syncthreads();

    uint4 w[32];
    #pragma unroll
    for (int k2 = 0; k2 < 32; ++k2) w[k2] = W4[k2 * 256 + tid];
    const float4 bc = bc4[tid];

    const unsigned* __restrict__ ob32 = (const unsigned*)obsh;
    for (int n = 0; n < 64; ++n) {
        float4 a = bc;
        #pragma unroll
        for (int k2 = 0; k2 < 32; ++k2) {
            unsigned xv = ob32[n * 32 + k2];
            a.x = dot2(w[k2].x, xv, a.x);
            a.y = dot2(w[k2].y, xv, a.y);
            a.z = dot2(w[k2].z, xv, a.z);
            a.w = dot2(w[k2].w, xv, a.w);
        }
        // R5 fix: row must be scaled by 256 (was (base>>6) + n*256 + tid)
        zx4[(row0 + n) * 256 + tid] = make_uint2(packh(a.x, a.y), packh(a.z, a.w));
    }
}

// ---------------- segment extraction ----------------
__global__ void seg_kernel(const float* __restrict__ M, uint2* __restrict__ segs,
                           unsigned* __restrict__ cnt) {
    int b = blockIdx.x, tid = threadIdx.x;
    int base = b * T_SEQ;
    for (int t = tid; t < T_SEQ; t += 256) {
        bool start = (t == 0) || (M[base + t] != 0.f);
        if (!start) continue;
        int t2 = t + 1;
        while (t2 < T_SEQ && M[base + t2] == 0.f) ++t2;
        unsigned idx = atomicAdd(&cnt[0], 1u);
        segs[idx] = make_uint2((unsigned)(base + t), (unsigned)(t2 - t));
    }
}

// ---------------- counting sort by length, descending (LPT) ----------------
__global__ void sort_kernel(const uint2* __restrict__ segs, uint2* __restrict__ out,
                            unsigned* __restrict__ cnt) {
    __shared__ unsigned hist[2049];
    __shared__ unsigned partial[256];
    __shared__ unsigned ofs[2049];
    int tid = threadIdx.x;
    unsigned n = cnt[0];
    for (int i = tid; i < 2049; i += 256) hist[i] = 0u;
    __syncthreads();
    for (unsigned i = tid; i < n; i += 256) atomicAdd(&hist[segs[i].y], 1u);
    __syncthreads();
    int cs = tid * 8 + 1;
    unsigned s = 0;
    #pragma unroll
    for (int i = 0; i < 8; ++i) s += hist[cs + i];
    partial[tid] = s;
    __syncthreads();
    if (tid == 0) {
        unsigned run = 0;
        for (int t = 255; t >= 0; --t) { unsigned p = partial[t]; partial[t] = run; run += p; }
    }
    __syncthreads();
    unsigned run = partial[tid];
    #pragma unroll
    for (int i = 7; i >= 0; --i) { int bin = cs + i; ofs[bin] = run; run += hist[bin]; }
    __syncthreads();
    for (unsigned i = tid; i < n; i += 256) {
        uint2 sg = segs[i];
        unsigned pos = atomicAdd(&ofs[sg.y], 1u);
        out[pos] = sg;
    }
}

// ---------------- one lockstep step for N active slots ----------------
// Z0 = 32: zx path (h-only K, acc init from zx4). Z0 = 0: obs folded, init bc4.
template <int N, int Z0>
__device__ __forceinline__ void step_n(unsigned (*X)[NK2], float (&c)[GSLOTS],
                                       const uint4* __restrict__ W4,
                                       const float4* __restrict__ bc4,
                                       const uint2* __restrict__ zx4,
                                       const unsigned* ssn, float* __restrict__ out,
                                       int tid) {
    float4 acc[N];
    if (Z0 == 0) {
        const float4 b = bc4[tid];
        #pragma unroll
        for (int g = 0; g < N; ++g) acc[g] = b;
    } else {
        #pragma unroll
        for (int g = 0; g < N; ++g) {
            uint2 z = zx4[(size_t)ssn[g] * 256 + tid];
            acc[g].x = __half2float(__ushort_as_half((unsigned short)(z.x & 0xffffu)));
            acc[g].y = __half2float(__ushort_as_half((unsigned short)(z.x >> 16)));
            acc[g].z = __half2float(__ushort_as_half((unsigned short)(z.y & 0xffffu)));
            acc[g].w = __half2float(__ushort_as_half((unsigned short)(z.y >> 16)));
        }
    }
    for (int k2 = Z0; k2 < NK2; k2 += 4) {
        uint4 w0 = W4[(k2 + 0) * 256 + tid];
        uint4 w1 = W4[(k2 + 1) * 256 + tid];
        uint4 w2 = W4[(k2 + 2) * 256 + tid];
        uint4 w3 = W4[(k2 + 3) * 256 + tid];
        #pragma unroll
        for (int g = 0; g < N; ++g) {
            const uint4 xv = *(const uint4*)&X[g][k2];
            acc[g].x = dot2(w0.x, xv.x, acc[g].x);
            acc[g].y = dot2(w0.y, xv.x, acc[g].y);
            acc[g].z = dot2(w0.z, xv.x, acc[g].z);
            acc[g].w = dot2(w0.w, xv.x, acc[g].w);
            acc[g].x = dot2(w1.x, xv.y, acc[g].x);
            acc[g].y = dot2(w1.y, xv.y, acc[g].y);
            acc[g].z = dot2(w1.z, xv.y, acc[g].z);
            acc[g].w = dot2(w1.w, xv.y, acc[g].w);
            acc[g].x = dot2(w2.x, xv.z, acc[g].x);
            acc[g].y = dot2(w2.y, xv.z, acc[g].y);
            acc[g].z = dot2(w2.z, xv.z, acc[g].z);
            acc[g].w = dot2(w2.w, xv.z, acc[g].w);
            acc[g].x = dot2(w3.x, xv.w, acc[g].x);
            acc[g].y = dot2(w3.y, xv.w, acc[g].y);
            acc[g].z = dot2(w3.z, xv.w, acc[g].z);
            acc[g].w = dot2(w3.w, xv.w, acc[g].w);
        }
    }
    float hv[N];
    #pragma unroll
    for (int g = 0; g < N; ++g) {
        float i = sigm(acc[g].x);
        float f = sigm(acc[g].y);
        float gg = tanh_(acc[g].z);
        float o = sigm(acc[g].w);
        c[g] = fmaf(f, c[g], i * gg);        // register-private, safe pre-barrier
        hv[g] = o * tanh_(c[g]);
    }
    __syncthreads();   // all X reads complete before overwriting h
    #pragma unroll
    for (int g = 0; g < N; ++g) {
        ((__half*)X[g])[2 * ZK2 + tid] = __float2half(hv[g]);
        out[(size_t)ssn[g] * HID + tid] = hv[g];
    }
}

// ---------------- persistent segment-parallel LSTM ----------------
template <int Z0>
__global__ __launch_bounds__(256, 2)
void lstm_kernel(const float* __restrict__ obs, const float* __restrict__ S,
                 const float* __restrict__ M,
                 const uint4* __restrict__ W4, const float4* __restrict__ bc4,
                 const uint2* __restrict__ zx4,
                 const uint2* __restrict__ segs, unsigned* __restrict__ cnt,
                 float* __restrict__ out) {
    __shared__ unsigned X[GSLOTS][NK2];    // f16 pairs; [0..31]=obs, [32..159]=h
    __shared__ float    Cb[GSLOTS][HID];   // bounce buffer for compaction only
    __shared__ unsigned ssn[GSLOTS], send[GSLOTS];
    __shared__ int      sact[GSLOTS], sfresh[GSLOTS];
    __shared__ int      sh_nact, sh_nmig;
    __shared__ unsigned sh_mask;
    __shared__ int      msrc[GSLOTS], mdst[GSLOTS];

    const int tid = threadIdx.x;
    const unsigned nseg = cnt[0];
    float c[GSLOTS];
    if (tid < GSLOTS) sact[tid] = 0;
    __syncthreads();

    for (;;) {
        // ---- control: advance / finish / refill
        if (tid < GSLOTS) {
            int g = tid;
            if (sact[g]) {
                unsigned nn = ssn[g] + 1;
                if (nn >= send[g]) sact[g] = 0; else ssn[g] = nn;
            }
            sfresh[g] = 0;
            if (!sact[g]) {
                unsigned idx = atomicAdd(&cnt[1], 1u);
                if (idx < nseg) {
                    uint2 sg = segs[idx];
                    ssn[g] = sg.x; send[g] = sg.x + sg.y;
                    sact[g] = 1; sfresh[g] = 1;
                }
            }
        }
        if (tid < 64) {
            unsigned long long bal = __ballot(tid < GSLOTS && sact[tid]);
            if (tid == 0) {
                unsigned m = (unsigned)(bal & 0xFFFFull);
                sh_mask = m;
                sh_nact = __popc(m);
            }
        }
        __syncthreads();                        // A
        const unsigned mask = sh_mask;
        if (mask == 0u) break;
        const int nact = sh_nact;

        // ---- compaction (holes in prefix): LDS bounce keeps c statically indexed
        if (mask != ((1u << nact) - 1u)) {
            if (tid == 0) {
                int w = 0, nm = 0;
                for (int g = 0; g < GSLOTS; ++g) if (sact[g]) {
                    if (g != w) {
                        msrc[nm] = g; mdst[nm] = w; ++nm;
                        ssn[w] = ssn[g]; send[w] = send[g];
                        sfresh[w] = sfresh[g];
                        sact[w] = 1; sact[g] = 0;
                    }
                    ++w;
                }
                sh_nmig = nm;
            }
            #pragma unroll
            for (int g = 0; g < GSLOTS; ++g) Cb[g][tid] = c[g];
            __syncthreads();
            const int nm = sh_nmig;
            for (int i = 0; i < nm; ++i) {      // ascending: dst<src, safe
                int s = msrc[i], d = mdst[i];
                if (tid < NK2) X[d][tid] = X[s][tid];
                Cb[d][tid] = Cb[s][tid];
            }
            __syncthreads();
            #pragma unroll
            for (int g = 0; g < GSLOTS; ++g) c[g] = Cb[g][tid];
        }

        // ---- fresh-slot init (h, c); obs staging for the no-zx path
        #pragma unroll
        for (int g = 0; g < GSLOTS; ++g) {
            if (g < nact && sfresh[g]) {
                unsigned n0 = ssn[g];
                float h0 = 0.f, c0 = 0.f;
                if ((n0 & (T_SEQ - 1)) == 0u && M[n0] == 0.f) {
                    unsigned b = n0 >> 11;
                    h0 = S[b * 512 + tid];
                    c0 = S[b * 512 + 256 + tid];
                }
                ((__half*)X[g])[2 * ZK2 + tid] = __float2half(h0);
                c[g] = c0;
            }
        }
        if (Z0 == 0) {
            int g0 = (tid >> 6), e = tid & 63;
            #pragma unroll
            for (int p = 0; p < 4; ++p) {
                int g = g0 + 4 * p;
                if (g < nact)
                    ((__half*)X[g])[e] = __float2half(obs[(size_t)ssn[g] * OBS + e]);
            }
        }
        __syncthreads();                        // B: X ready

        switch (nact) {
            case 1:  step_n<1,  Z0>(X, c, W4, bc4, zx4, ssn, out, tid); break;
            case 2:  step_n<2,  Z0>(X, c, W4, bc4, zx4, ssn, out, tid); break;
            case 3:  step_n<3,  Z0>(X, c, W4, bc4, zx4, ssn, out, tid); break;
            case 4:  step_n<4,  Z0>(X, c, W4, bc4, zx4, ssn, out, tid); break;
            case 5:  step_n<5,  Z0>(X, c, W4, bc4, zx4, ssn, out, tid); break;
            case 6:  step_n<6,  Z0>(X, c, W4, bc4, zx4, ssn, out, tid); break;
            case 7:  step_n<7,  Z0>(X, c, W4, bc4, zx4, ssn, out, tid); break;
            case 8:  step_n<8,  Z0>(X, c, W4, bc4, zx4, ssn, out, tid); break;
            case 9:  step_n<9,  Z0>(X, c, W4, bc4, zx4, ssn, out, tid); break;
            case 10: step_n<10, Z0>(X, c, W4, bc4, zx4, ssn, out, tid); break;
            case 11: step_n<11, Z0>(X, c, W4, bc4, zx4, ssn, out, tid); break;
            case 12: step_n<12, Z0>(X, c, W4, bc4, zx4, ssn, out, tid); break;
            case 13: step_n<13, Z0>(X, c, W4, bc4, zx4, ssn, out, tid); break;
            case 14: step_n<14, Z0>(X, c, W4, bc4, zx4, ssn, out, tid); break;
            case 15: step_n<15, Z0>(X, c, W4, bc4, zx4, ssn, out, tid); break;
            default: step_n<16, Z0>(X, c, W4, bc4, zx4, ssn, out, tid); break;
        }
        __syncthreads();                        // C
    }
}

// ---------------- launch ----------------
extern "C" void kernel_launch(void* const* d_in, const int* in_sizes, int n_in,
                              void* d_out, int out_size, void* d_ws, size_t ws_size,
                              hipStream_t stream) {
    const float* obs     = (const float*)d_in[0];
    const float* S       = (const float*)d_in[1];
    const float* M       = (const float*)d_in[2];
    const float* W_embed = (const float*)d_in[3];
    const float* b_embed = (const float*)d_in[4];
    const float* kern    = (const float*)d_in[5];
    const float* rec     = (const float*)d_in[6];
    const float* bias    = (const float*)d_in[7];
    float* out = (float*)d_out;

    // ws carve: W4 | bc4 | cnt | segs | ssort | zx4(optional)
    uint4*    W4    = (uint4*)d_ws;                       // 160*256*16 = 640 KB
    float4*   bc4   = (float4*)(W4 + NK2 * 256);          // 4 KB
    unsigned* cnt   = (unsigned*)(bc4 + 256);             // 64 B
    uint2*    segs  = (uint2*)(cnt + 16);                 // 512 KB
    uint2*    ssort = segs + MAXSEG;                      // 512 KB
    uint2*    zx4   = ssort + MAXSEG;                     // 65536*256*8 = 134.2 MB
    size_t    zx_need = (size_t)((char*)zx4 - (char*)d_ws) + (size_t)65536 * 256 * 8;
    const bool use_zx = (ws_size >= zx_need);             // uniform across calls

    hipLaunchKernelGGL(prep_kernel, dim3(NK2 + 1), dim3(256), 0, stream,
                       W_embed, b_embed, kern, rec, bias, W4, bc4, cnt);
    hipLaunchKernelGGL(seg_kernel, dim3(NBATCH), dim3(256), 0, stream, M, segs, cnt);
    hipLaunchKernelGGL(sort_kernel, dim3(1), dim3(256), 0, stream, segs, ssort, cnt);
    if (use_zx) {
        hipLaunchKernelGGL(zx_kernel, dim3(1024), dim3(256), 0, stream, obs, W4, bc4, zx4);
        hipLaunchKernelGGL((lstm_kernel<ZK2>), dim3(NWG), dim3(256), 0, stream,
                           obs, S, M, W4, bc4, zx4, ssort, cnt, out);
    } else {
        hipLaunchKernelGGL((lstm_kernel<0>), dim3(NWG), dim3(256), 0, stream,
                           obs, S, M, W4, bc4, zx4, ssort, cnt, out);
    }
}